// Round 9
// baseline (618.775 us; speedup 1.0000x reference)
//
#include <hip/hip_runtime.h>
#include <stdint.h>

typedef unsigned short u16;
typedef unsigned char u8;
typedef unsigned long long u64;
typedef __attribute__((ext_vector_type(8))) short bf16x8;
typedef __attribute__((ext_vector_type(4))) float f32x4;
typedef __attribute__((ext_vector_type(16))) float f32x16;
typedef __attribute__((ext_vector_type(8))) int i32x8;

#define KLOG2E 0.18033688011112043f   // SCALE(0.125) * log2(e)
#define QSCL 184.66496523378732f      // KLOG2E * 1024
#define SINV 0.0001220703125f         // 2^-13
#define EXP2F(x) __builtin_amdgcn_exp2f(x)
#define WAITV(n) asm volatile("s_waitcnt vmcnt(" #n ")" ::: "memory")

__device__ __forceinline__ u16 f2bf(float f) {
  union { float f; unsigned u; } v; v.f = f;
  unsigned r = v.u + 0x7fffu + ((v.u >> 16) & 1u);
  return (u16)(r >> 16);
}
__device__ __forceinline__ float bf2f(u16 u) {
  union { unsigned u; float f; } v; v.u = ((unsigned)u) << 16;
  return v.f;
}
__device__ __forceinline__ u8 f2fp8(float f) {
  return (u8)(__builtin_amdgcn_cvt_pk_fp8_f32(f, f, 0, false) & 0xFF);
}

__device__ __forceinline__ void gload16(const void* g, void* l) {
  __builtin_amdgcn_global_load_lds(
      (const __attribute__((address_space(1))) unsigned int*)g,
      (__attribute__((address_space(3))) unsigned int*)l, 16, 0, 0);
}

__global__ void cvt_f32_bf16(const float4* __restrict__ s, uint2* __restrict__ d, int n4) {
  int i = blockIdx.x * blockDim.x + threadIdx.x;
  int stride = gridDim.x * blockDim.x;
  for (; i < n4; i += stride) {
    float4 v = s[i];
    uint2 o;
    o.x = (unsigned)f2bf(v.x) | ((unsigned)f2bf(v.y) << 16);
    o.y = (unsigned)f2bf(v.z) | ((unsigned)f2bf(v.w) << 16);
    d[i] = o;
  }
}

// C = A @ B^T, A [M,768] bf16, B [N,768] bf16, 128x128 tile, 4 waves.
// MODE 0: col<768 -> Qb bf16 [row][768]; col>=768 -> Kf8 fp8 x8 (natural d order)
// MODE 1: vT+cb store; MODE 2: f32 C + bias[col].
template <int MODE>
__global__ __launch_bounds__(256, 2) void gemm_bt(
    const u16* __restrict__ A, const u16* __restrict__ Bm,
    void* __restrict__ Cp, void* __restrict__ Cp2,
    const float* __restrict__ bias, int ldc) {
  __shared__ u16 Ab[128 * 32];
  __shared__ u16 Bb[128 * 32];
  const int tid = threadIdx.x;
  const int l = tid & 63, w = tid >> 6;
  const int g = l >> 4, l15 = l & 15;
  const int wr = w >> 1, wc = w & 1;
  const int rowbase = blockIdx.y * 128, colbase = blockIdx.x * 128;

  f32x4 acc[4][4] = {};
  const char* Abase = (const char*)A + (size_t)rowbase * 1536;
  const char* Bbase = (const char*)Bm + (size_t)colbase * 1536;

  for (int kk = 0; kk < 768; kk += 32) {
    __syncthreads();
#pragma unroll
    for (int p = 0; p < 2; ++p) {
      int o = p * 4096 + w * 1024 + l * 16;
      int row = o >> 6, cb = o & 63;
      gload16(Abase + (size_t)row * 1536 + kk * 2 + cb, &Ab[(p * 4096 + w * 1024) / 2]);
      gload16(Bbase + (size_t)row * 1536 + kk * 2 + cb, &Bb[(p * 4096 + w * 1024) / 2]);
    }
    __syncthreads();
    bf16x8 af[4], bfr[4];
#pragma unroll
    for (int i = 0; i < 4; ++i) {
      af[i] = *(const bf16x8*)&Ab[(wr * 64 + i * 16 + l15) * 32 + g * 8];
      bfr[i] = *(const bf16x8*)&Bb[(wc * 64 + i * 16 + l15) * 32 + g * 8];
    }
#pragma unroll
    for (int mi = 0; mi < 4; ++mi)
#pragma unroll
      for (int ni = 0; ni < 4; ++ni)
        acc[mi][ni] = __builtin_amdgcn_mfma_f32_16x16x32_bf16(af[mi], bfr[ni], acc[mi][ni], 0, 0, 0);
  }

#pragma unroll
  for (int mi = 0; mi < 4; ++mi)
#pragma unroll
    for (int ni = 0; ni < 4; ++ni)
#pragma unroll
      for (int r = 0; r < 4; ++r) {
        int row = rowbase + wr * 64 + mi * 16 + g * 4 + r;
        int col = colbase + wc * 64 + ni * 16 + l15;
        float v = acc[mi][ni][r];
        if (MODE == 0) {
          if (col < 768) {
            ((u16*)Cp)[(size_t)row * 768 + col] = f2bf(v);
          } else {
            ((u8*)Cp2)[(size_t)row * 768 + (col - 768)] = f2fp8(v * 8.0f);
          }
        } else if (MODE == 2) {
          ((float*)Cp)[(size_t)row * ldc + col] = v + bias[col];
        } else {
          int b = col >> 10, nn = col & 1023;
          if (row < 768) {
            ((u16*)Cp)[(size_t)b * 786432 + (size_t)row * 1024 + nn] = f2bf(v + bias[row]);
          } else if (row < 780) {
            ((float*)Cp2)[(size_t)b * 12288 + (size_t)(row - 768) * 1024 + nn] = v * KLOG2E;
          }
        }
      }
}

// Flash attention v9: MX-scaled fp8 QK^T 32x32x64, 32q/wave, P in-register,
// 3-deep K pipeline + counted vmcnt. grid 768 (XCD-swizzled), 256 thr (4 waves).
__global__ __launch_bounds__(256, 2) void attn9(
    const u16* __restrict__ Qb,   // [B*N][768] bf16 (q_shared)
    const u8* __restrict__ Kf8,   // [B*N][768] fp8 e4m3 x8
    const u16* __restrict__ vT,   // [B][768][1024] bf16
    const float* __restrict__ cb, // [B][12][1024], pre-scaled by KLOG2E
    const float* __restrict__ Wmix,
    u16* __restrict__ OH)         // [B*N][768] bf16
{
  __shared__ u8 Kb[3][8192];    // 3-deep: 64 k-rows x 128B fp8 chunk, 16B-slot swz
  __shared__ u16 Vb[2][4096];   // dbuf: 64 d-rows x 128B (64 k bf16), 16B-slot swz

  const int gid = blockIdx.x;
  const int b = gid & 7;
  const int within = gid >> 3;               // 0..95
  const int h = within % 12, qt = within / 12;  // qt 0..7
  const int tid = threadIdx.x;
  const int lane = tid & 63, w = tid >> 6;
  const int c = lane & 31, hi = lane >> 5;

  const u8* Ksrc = Kf8 + (size_t)b * 786432;
  const char* Vsrc = (const char*)vT + (size_t)(b * 12 + h) * 131072;
  const float* cbp = cb + (size_t)(b * 12 + h) * 1024;

  auto STK = [&](int kt2, int ch2, int buf) {
#pragma unroll
    for (int p4 = 0; p4 < 2; ++p4) {
      int o = p4 * 4096 + tid * 16;
      int row = o >> 7, t = (o >> 4) & 7;
      gload16(Ksrc + (size_t)(kt2 * 64 + row) * 768 + ch2 * 128 + ((t ^ (row & 7)) * 16),
              (char*)Kb[buf] + o);
    }
  };
  auto STV = [&](int kt2, int buf) {
#pragma unroll
    for (int p4 = 0; p4 < 2; ++p4) {
      int o = p4 * 4096 + tid * 16;
      int row = o >> 7, t = (o >> 4) & 7;
      gload16(Vsrc + (size_t)row * 2048 + kt2 * 128 + ((t ^ (row & 7)) * 16),
              (char*)Vb[buf] + o);
    }
  };

  // issue first stages, then build Q (overlap)
  STK(0, 0, 0);
  STK(0, 1, 1);
  STV(0, 0);

  // ---- Q prologue: lane (c,hi) holds q-row (qt*128+w*32+c), dims D*64+hi*32+[0..31]
  i32x8 qreg[12];
  {
    const u16* qrow = Qb + ((size_t)b * 1024 + qt * 128 + w * 32 + c) * 768;
    const float* wmh = Wmix + h * 768;
#pragma unroll
    for (int D = 0; D < 12; ++D) {
      i32x8 qq;
#pragma unroll
      for (int j = 0; j < 4; ++j) {
        int off = D * 64 + hi * 32 + j * 8;
        bf16x8 qv = *(const bf16x8*)(qrow + off);
        float4 w0 = *(const float4*)(wmh + off);
        float4 w1 = *(const float4*)(wmh + off + 4);
        float q0 = bf2f((u16)qv[0]) * (w0.x * QSCL);
        float q1 = bf2f((u16)qv[1]) * (w0.y * QSCL);
        float q2 = bf2f((u16)qv[2]) * (w0.z * QSCL);
        float q3 = bf2f((u16)qv[3]) * (w0.w * QSCL);
        float q4 = bf2f((u16)qv[4]) * (w1.x * QSCL);
        float q5 = bf2f((u16)qv[5]) * (w1.y * QSCL);
        float q6 = bf2f((u16)qv[6]) * (w1.z * QSCL);
        float q7 = bf2f((u16)qv[7]) * (w1.w * QSCL);
        int a = __builtin_amdgcn_cvt_pk_fp8_f32(q0, q1, 0, false);
        a = __builtin_amdgcn_cvt_pk_fp8_f32(q2, q3, a, true);
        int b2 = __builtin_amdgcn_cvt_pk_fp8_f32(q4, q5, 0, false);
        b2 = __builtin_amdgcn_cvt_pk_fp8_f32(q6, q7, b2, true);
        qq[2 * j] = a;
        qq[2 * j + 1] = b2;
      }
      qreg[D] = qq;
    }
  }

  WAITV(4);
  __builtin_amdgcn_s_barrier();

  float m_run = -1e30f, lpart = 0.f;
  f32x16 oacc[2] = {};

  for (int kt = 0; kt < 16; ++kt) {
    // hoist cb loads (oldest vmem ops of this kt)
    float4 cv[8];
#pragma unroll
    for (int kg = 0; kg < 2; ++kg)
#pragma unroll
      for (int j = 0; j < 4; ++j)
        cv[kg * 4 + j] = *(const float4*)(cbp + kt * 64 + kg * 32 + 8 * j + 4 * hi);

    f32x16 sa[2] = {};
#pragma unroll
    for (int ch = 0; ch < 6; ++ch) {
      if (ch <= 3) STK(kt, ch + 2, (ch + 2) % 3);
      else if (kt < 15) STK(kt + 1, ch - 4, (ch + 2) % 3);
      if (ch == 3 && kt < 15) STV(kt + 1, (kt + 1) & 1);

      __builtin_amdgcn_s_setprio(1);
      const u8* kbuf = Kb[ch % 3];
#pragma unroll
      for (int dblk = 0; dblk < 2; ++dblk) {
        const int D = ch * 2 + dblk;
#pragma unroll
        for (int kg = 0; kg < 2; ++kg) {
          int r = kg * 32 + c;
          int s0 = dblk * 4 + hi * 2;
          const u8* kb = kbuf + r * 128;
          uint4 klo = *(const uint4*)(kb + ((s0 ^ (r & 7)) * 16));
          uint4 khi4 = *(const uint4*)(kb + (((s0 + 1) ^ (r & 7)) * 16));
          i32x8 af;
          af[0] = (int)klo.x; af[1] = (int)klo.y; af[2] = (int)klo.z; af[3] = (int)klo.w;
          af[4] = (int)khi4.x; af[5] = (int)khi4.y; af[6] = (int)khi4.z; af[7] = (int)khi4.w;
          sa[kg] = __builtin_amdgcn_mfma_scale_f32_32x32x64_f8f6f4(
              af, qreg[D], sa[kg], 0, 0, 0, 127, 0, 127);
        }
      }
      __builtin_amdgcn_s_setprio(0);

      if (ch == 0) { if (kt == 0) { WAITV(4); } else { WAITV(2); } }
      else if (ch == 1 || ch == 2) { WAITV(2); }
      else if (ch == 3) { if (kt < 15) { WAITV(4); } else { WAITV(2); } }
      else if (ch == 4) { if (kt < 15) { WAITV(4); } else { WAITV(0); } }
      else { if (kt < 15) { WAITV(2); } else { WAITV(0); } }
      __builtin_amdgcn_s_barrier();
    }

    // ---- softmax: lane (c,hi) holds k = kg*32 + (u&3) + 8*(u>>2) + 4*hi for q=c
    float fv[32];
    float pmax = -1e30f;
#pragma unroll
    for (int kg = 0; kg < 2; ++kg)
#pragma unroll
      for (int u = 0; u < 16; ++u) {
        float cbv = ((const float*)&cv[kg * 4 + (u >> 2)])[u & 3];
        float t = fmaf(sa[kg][u], SINV, cbv);
        fv[kg * 16 + u] = t;
        pmax = fmaxf(pmax, t);
      }
    pmax = fmaxf(pmax, __shfl_xor(pmax, 32));
    if (__ballot(pmax > m_run)) {
      float mnew = fmaxf(m_run, pmax);
      float alpha = EXP2F(m_run - mnew);
      lpart *= alpha;
      oacc[0] *= alpha;
      oacc[1] *= alpha;
      m_run = mnew;
    }
    float rs = 0.f;
#pragma unroll
    for (int u2 = 0; u2 < 32; ++u2) {
      fv[u2] = EXP2F(fv[u2] - m_run);
      rs += fv[u2];
    }
    rs += __shfl_xor(rs, 32);
    lpart += rs;

    // ---- P pack in-register (v4-verified recipe) + PV (8x 32x32x16 bf16)
#pragma unroll
    for (int kg = 0; kg < 2; ++kg) {
      const float* pv = &fv[kg * 16];
      bf16x8 pf[2];
#pragma unroll
      for (int win = 0; win < 2; ++win) {
        unsigned xw, yw, zw, tw;
        asm("v_cvt_pk_bf16_f32 %0, %1, %2" : "=v"(xw) : "v"(pv[win * 8 + 0]), "v"(pv[win * 8 + 1]));
        asm("v_cvt_pk_bf16_f32 %0, %1, %2" : "=v"(yw) : "v"(pv[win * 8 + 2]), "v"(pv[win * 8 + 3]));
        asm("v_cvt_pk_bf16_f32 %0, %1, %2" : "=v"(zw) : "v"(pv[win * 8 + 4]), "v"(pv[win * 8 + 5]));
        asm("v_cvt_pk_bf16_f32 %0, %1, %2" : "=v"(tw) : "v"(pv[win * 8 + 6]), "v"(pv[win * 8 + 7]));
        asm volatile("v_permlane32_swap_b32 %0, %1" : "+v"(xw), "+v"(zw));
        asm volatile("v_permlane32_swap_b32 %0, %1" : "+v"(yw), "+v"(tw));
        union { unsigned u[4]; bf16x8 v; } bu;
        bu.u[0] = xw; bu.u[1] = yw; bu.u[2] = zw; bu.u[3] = tw;
        pf[win] = bu.v;
      }
#pragma unroll
      for (int win = 0; win < 2; ++win)
#pragma unroll
        for (int dg = 0; dg < 2; ++dg) {
          int rd = dg * 32 + c;
          int sv = kg * 4 + win * 2 + hi;
          bf16x8 vf = *(const bf16x8*)((const char*)Vb[kt & 1] + rd * 128 +
                                       ((sv ^ (rd & 7)) * 16));
          oacc[dg] = __builtin_amdgcn_mfma_f32_32x32x16_bf16(vf, pf[win], oacc[dg], 0, 0, 0);
        }
    }
  }

  // ---- epilogue: oacc[dg][u] = O[d = dg*32+(u&3)+8*(u>>2)+4*hi][q=c]
  float rdiv = 1.f / lpart;
  int n = qt * 128 + w * 32 + c;
  size_t nrow = ((size_t)b * 1024 + n) * 768 + h * 64;
#pragma unroll
  for (int dg = 0; dg < 2; ++dg)
#pragma unroll
    for (int j = 0; j < 4; ++j) {
      u64 pk = (u64)f2bf(oacc[dg][4 * j + 0] * rdiv) |
               ((u64)f2bf(oacc[dg][4 * j + 1] * rdiv) << 16) |
               ((u64)f2bf(oacc[dg][4 * j + 2] * rdiv) << 32) |
               ((u64)f2bf(oacc[dg][4 * j + 3] * rdiv) << 48);
      *(u64*)&OH[nrow + dg * 32 + 8 * j + 4 * hi] = pk;
    }
}

static inline int cvtblocks(int n4) {
  int nb = (n4 + 255) / 256;
  return nb > 2048 ? 2048 : nb;
}

extern "C" void kernel_launch(void* const* d_in, const int* in_sizes, int n_in,
                              void* d_out, int out_size, void* d_ws, size_t ws_size,
                              hipStream_t stream) {
  (void)in_sizes; (void)n_in; (void)out_size; (void)ws_size;
  const float* x = (const float*)d_in[0];
  const float* Wq = (const float*)d_in[1];
  const float* Wk = (const float*)d_in[2];
  const float* Wv = (const float*)d_in[3];
  const float* bv = (const float*)d_in[4];
  const float* Wmix = (const float*)d_in[5];
  const float* Wcb = (const float*)d_in[6];
  const float* Wproj = (const float*)d_in[7];
  const float* bproj = (const float*)d_in[8];
  float* out = (float*)d_out;

  char* ws = (char*)d_ws;
  u16* xbf = (u16*)(ws);                 // 12582912 B
  u16* Wqk = (u16*)(ws + 12582912);      // 2359296 B
  u16* Wvcb = (u16*)(ws + 14942208);     // 1376256 B
  u16* Wpj = (u16*)(ws + 16318464);      // 1179648 B
  u16* Qb = (u16*)(ws + 17498112);       // 12582912 B
  u8* Kf8 = (u8*)(ws + 30081024);        // 6291456 B
  u16* vT = (u16*)(ws + 36372480);       // 12582912 B
  float* cbb = (float*)(ws + 48955392);  // 393216 B
  u16* OH = (u16*)(ws + 49348608);       // 12582912 B (end 61931520)

  cvt_f32_bf16<<<cvtblocks(1572864), 256, 0, stream>>>((const float4*)x, (uint2*)xbf, 1572864);
  cvt_f32_bf16<<<cvtblocks(147456), 256, 0, stream>>>((const float4*)Wq, (uint2*)Wqk, 147456);
  cvt_f32_bf16<<<cvtblocks(147456), 256, 0, stream>>>((const float4*)Wk, (uint2*)(Wqk + 589824), 147456);
  cvt_f32_bf16<<<cvtblocks(147456), 256, 0, stream>>>((const float4*)Wv, (uint2*)Wvcb, 147456);
  cvt_f32_bf16<<<cvtblocks(2304), 256, 0, stream>>>((const float4*)Wcb, (uint2*)(Wvcb + 589824), 2304);
  cvt_f32_bf16<<<cvtblocks(147456), 256, 0, stream>>>((const float4*)Wproj, (uint2*)Wpj, 147456);

  gemm_bt<0><<<dim3(12, 64), 256, 0, stream>>>(xbf, Wqk, Qb, Kf8, nullptr, 0);
  gemm_bt<1><<<dim3(64, 7), 256, 0, stream>>>(Wvcb, xbf, vT, cbb, bv, 0);
  attn9<<<dim3(768), 256, 0, stream>>>(Qb, Kf8, vT, cbb, Wmix, OH);
  gemm_bt<2><<<dim3(6, 64), 256, 0, stream>>>(OH, Wpj, out, nullptr, bproj, 768);
}

// Round 10
// 279.559 us; speedup vs baseline: 2.2134x; 2.2134x over previous
//
#include <hip/hip_runtime.h>
#include <stdint.h>

typedef unsigned short u16;
typedef unsigned char u8;
typedef unsigned long long u64;
typedef __attribute__((ext_vector_type(8))) short bf16x8;
typedef __attribute__((ext_vector_type(4))) float f32x4;
typedef __attribute__((ext_vector_type(16))) float f32x16;

#define KLOG2E 0.18033688011112043f   // SCALE(0.125) * log2(e)
#define QSCL 184.66496523378732f      // KLOG2E * 1024
#define SINV 0.0001220703125f         // 2^-13
#define EXP2F(x) __builtin_amdgcn_exp2f(x)
#define WAITV(n) asm volatile("s_waitcnt vmcnt(" #n ")" ::: "memory")

__device__ __forceinline__ u16 f2bf(float f) {
  union { float f; unsigned u; } v; v.f = f;
  unsigned r = v.u + 0x7fffu + ((v.u >> 16) & 1u);
  return (u16)(r >> 16);
}
__device__ __forceinline__ float bf2f(u16 u) {
  union { unsigned u; float f; } v; v.u = ((unsigned)u) << 16;
  return v.f;
}
__device__ __forceinline__ u8 f2fp8(float f) {
  return (u8)(__builtin_amdgcn_cvt_pk_fp8_f32(f, f, 0, false) & 0xFF);
}

__device__ __forceinline__ void gload16(const void* g, void* l) {
  __builtin_amdgcn_global_load_lds(
      (const __attribute__((address_space(1))) unsigned int*)g,
      (__attribute__((address_space(3))) unsigned int*)l, 16, 0, 0);
}

__global__ void cvt_f32_bf16(const float4* __restrict__ s, uint2* __restrict__ d, int n4) {
  int i = blockIdx.x * blockDim.x + threadIdx.x;
  int stride = gridDim.x * blockDim.x;
  for (; i < n4; i += stride) {
    float4 v = s[i];
    uint2 o;
    o.x = (unsigned)f2bf(v.x) | ((unsigned)f2bf(v.y) << 16);
    o.y = (unsigned)f2bf(v.z) | ((unsigned)f2bf(v.w) << 16);
    d[i] = o;
  }
}

// C = A @ B^T, A [M,768] bf16, B [N,768] bf16, 128x128 tile, 4 waves.
// MODE 0: col<768 -> Qb bf16 [row][768]; col>=768 -> Kf8 fp8 x8, with per-row
//         8B-half swap baked (d ^= ((n>>3)&1)<<3) for conflict-free attn reads.
// MODE 1: vT+cb store; MODE 2: f32 C + bias[col].
template <int MODE>
__global__ __launch_bounds__(256, 2) void gemm_bt(
    const u16* __restrict__ A, const u16* __restrict__ Bm,
    void* __restrict__ Cp, void* __restrict__ Cp2,
    const float* __restrict__ bias, int ldc) {
  __shared__ u16 Ab[128 * 32];
  __shared__ u16 Bb[128 * 32];
  const int tid = threadIdx.x;
  const int l = tid & 63, w = tid >> 6;
  const int g = l >> 4, l15 = l & 15;
  const int wr = w >> 1, wc = w & 1;
  const int rowbase = blockIdx.y * 128, colbase = blockIdx.x * 128;

  f32x4 acc[4][4] = {};
  const char* Abase = (const char*)A + (size_t)rowbase * 1536;
  const char* Bbase = (const char*)Bm + (size_t)colbase * 1536;

  for (int kk = 0; kk < 768; kk += 32) {
    __syncthreads();
#pragma unroll
    for (int p = 0; p < 2; ++p) {
      int o = p * 4096 + w * 1024 + l * 16;
      int row = o >> 6, cb = o & 63;
      gload16(Abase + (size_t)row * 1536 + kk * 2 + cb, &Ab[(p * 4096 + w * 1024) / 2]);
      gload16(Bbase + (size_t)row * 1536 + kk * 2 + cb, &Bb[(p * 4096 + w * 1024) / 2]);
    }
    __syncthreads();
    bf16x8 af[4], bfr[4];
#pragma unroll
    for (int i = 0; i < 4; ++i) {
      af[i] = *(const bf16x8*)&Ab[(wr * 64 + i * 16 + l15) * 32 + g * 8];
      bfr[i] = *(const bf16x8*)&Bb[(wc * 64 + i * 16 + l15) * 32 + g * 8];
    }
#pragma unroll
    for (int mi = 0; mi < 4; ++mi)
#pragma unroll
      for (int ni = 0; ni < 4; ++ni)
        acc[mi][ni] = __builtin_amdgcn_mfma_f32_16x16x32_bf16(af[mi], bfr[ni], acc[mi][ni], 0, 0, 0);
  }

#pragma unroll
  for (int mi = 0; mi < 4; ++mi)
#pragma unroll
    for (int ni = 0; ni < 4; ++ni)
#pragma unroll
      for (int r = 0; r < 4; ++r) {
        int row = rowbase + wr * 64 + mi * 16 + g * 4 + r;
        int col = colbase + wc * 64 + ni * 16 + l15;
        float v = acc[mi][ni][r];
        if (MODE == 0) {
          if (col < 768) {
            ((u16*)Cp)[(size_t)row * 768 + col] = f2bf(v);
          } else {
            int d = col - 768;
            int dp = d ^ ((((row) >> 3) & 1) << 3);
            ((u8*)Cp2)[(size_t)row * 768 + dp] = f2fp8(v * 8.0f);
          }
        } else if (MODE == 2) {
          ((float*)Cp)[(size_t)row * ldc + col] = v + bias[col];
        } else {
          int b = col >> 10, nn = col & 1023;
          if (row < 768) {
            ((u16*)Cp)[(size_t)b * 786432 + (size_t)row * 1024 + nn] = f2bf(v + bias[row]);
          } else if (row < 780) {
            ((float*)Cp2)[(size_t)b * 12288 + (size_t)(row - 768) * 1024 + nn] = v * KLOG2E;
          }
        }
      }
}

// Flash attention v10: fp8 32x32x16 QK^T (Nq=32/wave), P fully in-register,
// cb in LDS, 3-deep K pipeline + counted vmcnt + XCD swizzle.
// grid 768, 256 thr (4 waves x 32q).
__global__ __launch_bounds__(256, 2) void attn10(
    const u16* __restrict__ Qb,   // [B*N][768] bf16 (q_shared)
    const u8* __restrict__ Kf8,   // [B*N][768] fp8 e4m3 x8, half-swapped per row
    const u16* __restrict__ vT,   // [B][768][1024] bf16
    const float* __restrict__ cb, // [B][12][1024], pre-scaled by KLOG2E
    const float* __restrict__ Wmix,
    u16* __restrict__ OH)         // [B*N][768] bf16
{
  __shared__ u8 Kb[3][8192];    // 3-deep: 64 k-rows x 128B fp8 chunk, 16B-slot swz
  __shared__ u16 Vb[2][4096];   // dbuf: 64 d-rows x 128B (64 k bf16), 16B-slot swz
  __shared__ float cbL[1024];   // whole (b,h) content-bias row

  const int gid = blockIdx.x;
  const int b = gid & 7;
  const int within = gid >> 3;                  // 0..95
  const int h = within % 12, qt = within / 12;  // qt 0..7
  const int tid = threadIdx.x;
  const int lane = tid & 63, w = tid >> 6;
  const int c = lane & 31, hi = lane >> 5;
  const int hsw = (c >> 3) & 1;                 // bit3 of LDS k-row

  const u8* Ksrc = Kf8 + (size_t)b * 786432;
  const char* Vsrc = (const char*)vT + (size_t)(b * 12 + h) * 131072;
  const float* cbp = cb + (size_t)(b * 12 + h) * 1024;

  // ---- Q prologue: lane (c,hi): q-row qt*128+w*32+c, B-frag dims D*16+hi*8+[0..7]
  long qreg[48];
  {
    const u16* qrow = Qb + ((size_t)b * 1024 + qt * 128 + w * 32 + c) * 768;
    const float* wmh = Wmix + h * 768;
#pragma unroll
    for (int D = 0; D < 48; ++D) {
      int off = D * 16 + hi * 8;
      bf16x8 qv = *(const bf16x8*)(qrow + off);
      float4 w0 = *(const float4*)(wmh + off);
      float4 w1 = *(const float4*)(wmh + off + 4);
      float q0 = bf2f((u16)qv[0]) * (w0.x * QSCL);
      float q1 = bf2f((u16)qv[1]) * (w0.y * QSCL);
      float q2 = bf2f((u16)qv[2]) * (w0.z * QSCL);
      float q3 = bf2f((u16)qv[3]) * (w0.w * QSCL);
      float q4 = bf2f((u16)qv[4]) * (w1.x * QSCL);
      float q5 = bf2f((u16)qv[5]) * (w1.y * QSCL);
      float q6 = bf2f((u16)qv[6]) * (w1.z * QSCL);
      float q7 = bf2f((u16)qv[7]) * (w1.w * QSCL);
      int a = __builtin_amdgcn_cvt_pk_fp8_f32(q0, q1, 0, false);
      a = __builtin_amdgcn_cvt_pk_fp8_f32(q2, q3, a, true);
      int b2 = __builtin_amdgcn_cvt_pk_fp8_f32(q4, q5, 0, false);
      b2 = __builtin_amdgcn_cvt_pk_fp8_f32(q6, q7, b2, true);
      qreg[D] = (long)(((u64)(unsigned)b2 << 32) | (u64)(unsigned)a);
    }
  }

  auto STK = [&](int kt2, int ch2, int buf) {
#pragma unroll
    for (int p4 = 0; p4 < 2; ++p4) {
      int o = p4 * 4096 + tid * 16;
      int row = o >> 7, t = (o >> 4) & 7;
      gload16(Ksrc + (size_t)(kt2 * 64 + row) * 768 + ch2 * 128 + ((t ^ (row & 7)) * 16),
              (char*)Kb[buf] + o);
    }
  };
  auto STV = [&](int kt2, int buf) {
#pragma unroll
    for (int p4 = 0; p4 < 2; ++p4) {
      int o = p4 * 4096 + tid * 16;
      int row = o >> 7, t = (o >> 4) & 7;
      gload16(Vsrc + (size_t)row * 2048 + kt2 * 128 + ((t ^ (row & 7)) * 16),
              (char*)Vb[buf] + o);
    }
  };

  // ---- prologue stages: cb (1 op), K ch0/ch1, V kt0 — single full drain
  {
    int o = tid * 16;
    gload16((const char*)cbp + o, (char*)cbL + o);
  }
  STK(0, 0, 0);
  STK(0, 1, 1);
  STV(0, 0);
  WAITV(0);
  __builtin_amdgcn_s_barrier();

  float m_run = -1e30f, lpart = 0.f;
  f32x16 oac0 = {}, oac1 = {};

#pragma unroll 1
  for (int kt = 0; kt < 16; ++kt) {
    f32x16 sa0 = {}, sa1 = {};
#pragma unroll
    for (int ch = 0; ch < 6; ++ch) {
      // stage: phase p stages chunk p+2 (chunks 0,1 of kt+1 at p=4,5); V at p=1
      if (ch == 1 && kt < 15) STV(kt + 1, (kt + 1) & 1);
      if (ch <= 3) STK(kt, ch + 2, (ch + 2) % 3);
      else if (kt < 15) STK(kt + 1, ch - 4, (ch + 2) % 3);

      __builtin_amdgcn_s_setprio(1);
      const u8* kb0 = Kb[ch % 3] + c * 128 + ((hi ^ hsw) * 8);
#pragma unroll
      for (int s = 0; s < 8; ++s) {
        const u8* pK = kb0 + ((s ^ (c & 7)) << 4);
        long k0 = *(const long*)pK;
        long k1 = *(const long*)(pK + 4096);
        sa0 = __builtin_amdgcn_mfma_f32_32x32x16_fp8_fp8(k0, qreg[ch * 8 + s], sa0, 0, 0, 0);
        sa1 = __builtin_amdgcn_mfma_f32_32x32x16_fp8_fp8(k1, qreg[ch * 8 + s], sa1, 0, 0, 0);
      }
      __builtin_amdgcn_s_setprio(0);

      // counted waits: cover stage for next phase's compute; never drain mid-loop
      if (ch == 0) { WAITV(2); }
      else if (ch == 1) { if (kt < 15) { WAITV(4); } else { WAITV(2); } }
      else if (ch == 4 || ch == 5) { if (kt < 15) { WAITV(2); } else { WAITV(0); } }
      else { WAITV(2); }
      __builtin_amdgcn_s_barrier();
    }

    // ---- softmax (in place): lane holds k = kg*32 + (u&3)+8*(u>>2)+4*hi, q = c
    float cb0[16], cb1[16];
#pragma unroll
    for (int j = 0; j < 4; ++j) {
      float4 t0 = *(const float4*)&cbL[kt * 64 + 8 * j + 4 * hi];
      float4 t1 = *(const float4*)&cbL[kt * 64 + 32 + 8 * j + 4 * hi];
      cb0[4 * j] = t0.x; cb0[4 * j + 1] = t0.y; cb0[4 * j + 2] = t0.z; cb0[4 * j + 3] = t0.w;
      cb1[4 * j] = t1.x; cb1[4 * j + 1] = t1.y; cb1[4 * j + 2] = t1.z; cb1[4 * j + 3] = t1.w;
    }
    float pmax = -1e30f;
#pragma unroll
    for (int u = 0; u < 16; ++u) {
      sa0[u] = fmaf(sa0[u], SINV, cb0[u]);
      sa1[u] = fmaf(sa1[u], SINV, cb1[u]);
      pmax = fmaxf(pmax, fmaxf(sa0[u], sa1[u]));
    }
    pmax = fmaxf(pmax, __shfl_xor(pmax, 32));
    if (__ballot(pmax > m_run)) {
      float mnew = fmaxf(m_run, pmax);
      float alpha = EXP2F(m_run - mnew);
      lpart *= alpha;
      oac0 *= alpha;
      oac1 *= alpha;
      m_run = mnew;
    }
    float rs = 0.f;
#pragma unroll
    for (int u = 0; u < 16; ++u) {
      sa0[u] = EXP2F(sa0[u] - m_run); rs += sa0[u];
      sa1[u] = EXP2F(sa1[u] - m_run); rs += sa1[u];
    }
    rs += __shfl_xor(rs, 32);
    lpart += rs;

    // ---- P pack in-register (v9-verified) + PV: 2 kg x 2 win x 2 dg MFMAs
    const char* vb = (const char*)Vb[kt & 1];
#pragma unroll
    for (int kg = 0; kg < 2; ++kg) {
#pragma unroll
      for (int win = 0; win < 2; ++win) {
        float p0, p1, p2, p3, p4, p5, p6, p7;
        if (kg == 0) {
          p0 = sa0[win * 8 + 0]; p1 = sa0[win * 8 + 1]; p2 = sa0[win * 8 + 2]; p3 = sa0[win * 8 + 3];
          p4 = sa0[win * 8 + 4]; p5 = sa0[win * 8 + 5]; p6 = sa0[win * 8 + 6]; p7 = sa0[win * 8 + 7];
        } else {
          p0 = sa1[win * 8 + 0]; p1 = sa1[win * 8 + 1]; p2 = sa1[win * 8 + 2]; p3 = sa1[win * 8 + 3];
          p4 = sa1[win * 8 + 4]; p5 = sa1[win * 8 + 5]; p6 = sa1[win * 8 + 6]; p7 = sa1[win * 8 + 7];
        }
        unsigned xw, yw, zw, tw;
        asm("v_cvt_pk_bf16_f32 %0, %1, %2" : "=v"(xw) : "v"(p0), "v"(p1));
        asm("v_cvt_pk_bf16_f32 %0, %1, %2" : "=v"(yw) : "v"(p2), "v"(p3));
        asm("v_cvt_pk_bf16_f32 %0, %1, %2" : "=v"(zw) : "v"(p4), "v"(p5));
        asm("v_cvt_pk_bf16_f32 %0, %1, %2" : "=v"(tw) : "v"(p6), "v"(p7));
        asm volatile("v_permlane32_swap_b32 %0, %1" : "+v"(xw), "+v"(zw));
        asm volatile("v_permlane32_swap_b32 %0, %1" : "+v"(yw), "+v"(tw));
        union { unsigned u[4]; bf16x8 v; } bu;
        bu.u[0] = xw; bu.u[1] = yw; bu.u[2] = zw; bu.u[3] = tw;
#pragma unroll
        for (int dg = 0; dg < 2; ++dg) {
          int rd = dg * 32 + c;
          int sv = kg * 4 + win * 2 + hi;
          bf16x8 vf = *(const bf16x8*)(vb + rd * 128 + ((sv ^ (rd & 7)) * 16));
          if (dg == 0)
            oac0 = __builtin_amdgcn_mfma_f32_32x32x16_bf16(vf, bu.v, oac0, 0, 0, 0);
          else
            oac1 = __builtin_amdgcn_mfma_f32_32x32x16_bf16(vf, bu.v, oac1, 0, 0, 0);
        }
      }
    }
  }

  // ---- epilogue (v9-verified): oac[dg][u] = O[d = dg*32+(u&3)+8*(u>>2)+4*hi][q=c]
  float rdiv = 1.f / lpart;
  int n = qt * 128 + w * 32 + c;
  size_t nrow = ((size_t)b * 1024 + n) * 768 + h * 64;
#pragma unroll
  for (int dg = 0; dg < 2; ++dg)
#pragma unroll
    for (int j = 0; j < 4; ++j) {
      f32x16 oo = dg == 0 ? oac0 : oac1;
      u64 pk = (u64)f2bf(oo[4 * j + 0] * rdiv) |
               ((u64)f2bf(oo[4 * j + 1] * rdiv) << 16) |
               ((u64)f2bf(oo[4 * j + 2] * rdiv) << 32) |
               ((u64)f2bf(oo[4 * j + 3] * rdiv) << 48);
      *(u64*)&OH[nrow + dg * 32 + 8 * j + 4 * hi] = pk;
    }
}

static inline int cvtblocks(int n4) {
  int nb = (n4 + 255) / 256;
  return nb > 2048 ? 2048 : nb;
}

extern "C" void kernel_launch(void* const* d_in, const int* in_sizes, int n_in,
                              void* d_out, int out_size, void* d_ws, size_t ws_size,
                              hipStream_t stream) {
  (void)in_sizes; (void)n_in; (void)out_size; (void)ws_size;
  const float* x = (const float*)d_in[0];
  const float* Wq = (const float*)d_in[1];
  const float* Wk = (const float*)d_in[2];
  const float* Wv = (const float*)d_in[3];
  const float* bv = (const float*)d_in[4];
  const float* Wmix = (const float*)d_in[5];
  const float* Wcb = (const float*)d_in[6];
  const float* Wproj = (const float*)d_in[7];
  const float* bproj = (const float*)d_in[8];
  float* out = (float*)d_out;

  char* ws = (char*)d_ws;
  u16* xbf = (u16*)(ws);                 // 12582912 B
  u16* Wqk = (u16*)(ws + 12582912);      // 2359296 B
  u16* Wvcb = (u16*)(ws + 14942208);     // 1376256 B
  u16* Wpj = (u16*)(ws + 16318464);      // 1179648 B
  u16* Qb = (u16*)(ws + 17498112);       // 12582912 B
  u8* Kf8 = (u8*)(ws + 30081024);        // 6291456 B
  u16* vT = (u16*)(ws + 36372480);       // 12582912 B
  float* cbb = (float*)(ws + 48955392);  // 393216 B
  u16* OH = (u16*)(ws + 49348608);       // 12582912 B (end 61931520)

  cvt_f32_bf16<<<cvtblocks(1572864), 256, 0, stream>>>((const float4*)x, (uint2*)xbf, 1572864);
  cvt_f32_bf16<<<cvtblocks(147456), 256, 0, stream>>>((const float4*)Wq, (uint2*)Wqk, 147456);
  cvt_f32_bf16<<<cvtblocks(147456), 256, 0, stream>>>((const float4*)Wk, (uint2*)(Wqk + 589824), 147456);
  cvt_f32_bf16<<<cvtblocks(147456), 256, 0, stream>>>((const float4*)Wv, (uint2*)Wvcb, 147456);
  cvt_f32_bf16<<<cvtblocks(2304), 256, 0, stream>>>((const float4*)Wcb, (uint2*)(Wvcb + 589824), 2304);
  cvt_f32_bf16<<<cvtblocks(147456), 256, 0, stream>>>((const float4*)Wproj, (uint2*)Wpj, 147456);

  gemm_bt<0><<<dim3(12, 64), 256, 0, stream>>>(xbf, Wqk, Qb, Kf8, nullptr, 0);
  gemm_bt<1><<<dim3(64, 7), 256, 0, stream>>>(Wvcb, xbf, vT, cbb, bv, 0);
  attn10<<<dim3(768), 256, 0, stream>>>(Qb, Kf8, vT, cbb, Wmix, OH);
  gemm_bt<2><<<dim3(6, 64), 256, 0, stream>>>(OH, Wpj, out, nullptr, bproj, 768);
}